// Round 2
// baseline (129.355 us; speedup 1.0000x reference)
//
#include <hip/hip_runtime.h>

#define NP    44
#define B     400000
#define B4    (B / 4)            // 100000 float4 groups per particle
#define BLK   256
#define NBLK  2048               // 8 blocks/CU x 256 CU — one fully-resident round
#define TOT   (NP * B4)          // 4,400,000 float4 groups total
#define QW    (TOT / NBLK)       // 2148 per block
#define RW    (TOT % NBLK)       // first 896 blocks take one extra

// clang ext-vector type so __builtin_nontemporal_* accepts it directly
typedef float f4 __attribute__((ext_vector_type(4)));

// The whole bias-free 1->4->8->4->1 ReLU MLP is positively homogeneous in its
// scalar input:  y(x) = gp*x for x>=0,  gn*x for x<0.  Collapse per particle.
__device__ __forceinline__ void collapse_weights(
    const float* __restrict__ p1, const float* __restrict__ p2,
    const float* __restrict__ p3, const float* __restrict__ p4,
    float& gp, float& gn)
{
    float w1p[4], w1n[4];
#pragma unroll
    for (int k = 0; k < 4; ++k) {
        float w = p1[k];
        w1p[k] = fmaxf(w, 0.0f);
        w1n[k] = fminf(w, 0.0f);
    }

    float d2p[8], d2n[8];
#pragma unroll
    for (int i = 0; i < 8; ++i) {
        float ap = 0.0f, an = 0.0f;
#pragma unroll
        for (int k = 0; k < 4; ++k) {
            float w = p2[i * 4 + k];
            ap = fmaf(w, w1p[k], ap);
            an = fmaf(w, w1n[k], an);
        }
        d2p[i] = fmaxf(ap, 0.0f);   // relu branch for x>=0
        d2n[i] = fminf(an, 0.0f);   // relu branch for x<0  (relu(x*c) = x*min(c,0))
    }

    float f3p[4], f3n[4];
#pragma unroll
    for (int j = 0; j < 4; ++j) {
        float ap = 0.0f, an = 0.0f;
#pragma unroll
        for (int i = 0; i < 8; ++i) {
            float w = p3[j * 8 + i];
            ap = fmaf(w, d2p[i], ap);
            an = fmaf(w, d2n[i], an);
        }
        f3p[j] = fmaxf(ap, 0.0f);
        f3n[j] = fminf(an, 0.0f);
    }

    gp = 0.0f; gn = 0.0f;
#pragma unroll
    for (int j = 0; j < 4; ++j) {
        gp = fmaf(p4[j], f3p[j], gp);
        gn = fmaf(p4[j], f3n[j], gn);
    }
}

__device__ __forceinline__ f4 apply_gain(f4 v, float gp, float gn)
{
    f4 r;
    r.x = v.x * (v.x >= 0.0f ? gp : gn);
    r.y = v.y * (v.y >= 0.0f ? gp : gn);
    r.z = v.z * (v.z >= 0.0f ? gp : gn);
    r.w = v.w * (v.w >= 0.0f ? gp : gn);
    return r;
}

__global__ __launch_bounds__(BLK) void collapsed_mlp_kernel(
    const float* __restrict__ X,    // (NP, 1, B) — flat f4 layout == global idx
    const float* __restrict__ W1,   // (NP, 4, 1)
    const float* __restrict__ W2,   // (NP, 8, 4)
    const float* __restrict__ W3,   // (NP, 4, 8)
    const float* __restrict__ W4,   // (NP, 1, 4)
    float* __restrict__ out)        // (NP, 1, B)
{
    const int b     = blockIdx.x;
    const int tid   = threadIdx.x;
    // Balanced contiguous span: 2148 or 2149 f4 groups per block (±1 element).
    const int start = b * QW + min(b, RW);
    const int count = QW + (b < RW ? 1 : 0);

    const f4* Xp = (const f4*)X;
    f4*       Op = (f4*)out;

    // ---- Issue all streaming loads first (8 full + 1 predicated per thread) ----
    // 8*BLK = 2048 <= count always, so the first 8 are unconditional.
    f4 xv[8];
#pragma unroll
    for (int c = 0; c < 8; ++c)
        xv[c] = __builtin_nontemporal_load(&Xp[start + tid + c * BLK]);

    const int  extra = count - 8 * BLK;       // 100 or 101
    const bool has9  = tid < extra;
    f4 x9;
    if (has9)
        x9 = __builtin_nontemporal_load(&Xp[start + tid + 8 * BLK]);

    // ---- Per-block gains: span < B4, so at most ONE particle boundary ----
    // All wave-uniform math; overlaps the HBM load latency above.
    const int l0    = start / B4;
    const int l1    = (start + count - 1) / B4;
    const int bound = (l0 + 1) * B4;          // f4 index where particle l1 starts

    float g0p, g0n, g1p, g1n;
    collapse_weights(W1 + l0 * 4, W2 + l0 * 32, W3 + l0 * 32, W4 + l0 * 4, g0p, g0n);
    if (l1 != l0) {                            // uniform branch — ~43/2048 blocks take it
        collapse_weights(W1 + l1 * 4, W2 + l1 * 32, W3 + l1 * 32, W4 + l1 * 4, g1p, g1n);
    } else {
        g1p = g0p; g1n = g0n;
    }

    // ---- Apply + non-temporal store (output never re-read) ----
#pragma unroll
    for (int c = 0; c < 8; ++c) {
        const int   idx = start + tid + c * BLK;
        const float gp  = (idx >= bound) ? g1p : g0p;
        const float gn  = (idx >= bound) ? g1n : g0n;
        __builtin_nontemporal_store(apply_gain(xv[c], gp, gn), &Op[idx]);
    }
    if (has9) {
        const int   idx = start + tid + 8 * BLK;
        const float gp  = (idx >= bound) ? g1p : g0p;
        const float gn  = (idx >= bound) ? g1n : g0n;
        __builtin_nontemporal_store(apply_gain(x9, gp, gn), &Op[idx]);
    }
}

extern "C" void kernel_launch(void* const* d_in, const int* in_sizes, int n_in,
                              void* d_out, int out_size, void* d_ws, size_t ws_size,
                              hipStream_t stream) {
    const float* X  = (const float*)d_in[0];
    const float* W1 = (const float*)d_in[1];
    const float* W2 = (const float*)d_in[2];
    const float* W3 = (const float*)d_in[3];
    const float* W4 = (const float*)d_in[4];
    float* out = (float*)d_out;

    // 2048 persistent, perfectly balanced blocks: one resident round,
    // each streams ~68.8 KB in + ~68.8 KB out, contiguous.
    collapsed_mlp_kernel<<<dim3(NBLK), BLK, 0, stream>>>(X, W1, W2, W3, W4, out);
}